// Round 13
// baseline (410.675 us; speedup 1.0000x reference)
//
#include <hip/hip_runtime.h>
#include <stdint.h>

typedef __bf16 bf16;
typedef __attribute__((ext_vector_type(8))) __bf16 bf16x8;
typedef __attribute__((ext_vector_type(4))) float f32x4;

#define N_TOK 8192
#define C_DIM 1024
#define I_DIM 1408
#define NE 8
#define NEA 9
#define H_ROWS 25600

// ---- workspace byte offsets ----
#define CNT_OFF   0
#define OFFS_OFF  64
#define TT_OFF    128
#define BTOK_OFF  192
#define BP_OFF    (BTOK_OFF + NE * N_TOK * 4)
#define ROUTER_END (BP_OFF + NE * N_TOK * 4)
#define TSEL_OFF  ROUTER_END
#define TP0_OFF   (TSEL_OFF + N_TOK * 4)
#define TP1_OFF   (TP0_OFF + N_TOK * 4)
#define XB_OFF    (1u << 20)
#define WB1_OFF   (18u << 20)
#define WB2_OFF   (43u << 20)
#define WB3_OFF   (68u << 20)
#define H_OFF     (93u << 20)

__device__ __forceinline__ void gload16(const void* g, void* l) {
  __builtin_amdgcn_global_load_lds(
      (const __attribute__((address_space(1))) void*)g,
      (__attribute__((address_space(3))) void*)l, 16, 0, 0);
}

#define SCHED() __builtin_amdgcn_sched_barrier(0)
#define BAR()   __builtin_amdgcn_s_barrier()
#define VM0()   asm volatile("s_waitcnt vmcnt(0)" ::: "memory")

// ---------------- conversion fp32 -> bf16 ----------------
__global__ __launch_bounds__(256) void convert_kernel(
    const float* __restrict__ src, bf16* __restrict__ dst, int n8) {
  int i = blockIdx.x * 256 + threadIdx.x;
  if (i >= n8) return;
  const float* s = src + (size_t)i * 8;
  float4 a = *(const float4*)(s);
  float4 b = *(const float4*)(s + 4);
  bf16x8 v;
  v[0] = (bf16)a.x; v[1] = (bf16)a.y; v[2] = (bf16)a.z; v[3] = (bf16)a.w;
  v[4] = (bf16)b.x; v[5] = (bf16)b.y; v[6] = (bf16)b.z; v[7] = (bf16)b.w;
  *(bf16x8*)(dst + (size_t)i * 8) = v;
}

// ---------------- logits: wave per token, top-2, NO atomics ----------------
__global__ __launch_bounds__(256) void logits_kernel(
    const float* __restrict__ x, const float* __restrict__ Wg,
    int* __restrict__ tsel, float* __restrict__ tp0, float* __restrict__ tp1) {
  __shared__ __align__(16) float wg[NE * C_DIM];
  int t = threadIdx.x;
#pragma unroll
  for (int j = 0; j < 8; ++j) {
    int idx = (t + 256 * j) * 4;
    *(float4*)&wg[idx] = *(const float4*)&Wg[idx];
  }
  __syncthreads();
  int wid = t >> 6, lane = t & 63;
  int tok = blockIdx.x * 4 + wid;
  const float* xr = x + (size_t)tok * C_DIM;
  float acc[NE];
#pragma unroll
  for (int e = 0; e < NE; ++e) acc[e] = 0.f;
#pragma unroll
  for (int j = 0; j < 4; ++j) {
    int c4 = (lane + 64 * j) * 4;
    float4 xv = *(const float4*)&xr[c4];
#pragma unroll
    for (int e = 0; e < NE; ++e) {
      float4 wv = *(const float4*)&wg[e * C_DIM + c4];
      acc[e] += xv.x * wv.x + xv.y * wv.y + xv.z * wv.z + xv.w * wv.w;
    }
  }
  for (int o = 32; o >= 1; o >>= 1)
#pragma unroll
    for (int e = 0; e < NE; ++e) acc[e] += __shfl_xor(acc[e], o, 64);
  if (lane == 0) {
    float m = acc[0];
#pragma unroll
    for (int e = 1; e < NE; ++e) m = fmaxf(m, acc[e]);
    float p[NE], s = 0.f;
#pragma unroll
    for (int e = 0; e < NE; ++e) { p[e] = __expf(acc[e] - m); s += p[e]; }
    float inv = 1.f / s;
#pragma unroll
    for (int e = 0; e < NE; ++e) p[e] *= inv;
    int e0 = 0; float p0 = p[0];
#pragma unroll
    for (int e = 1; e < NE; ++e) if (p[e] > p0) { p0 = p[e]; e0 = e; }
    int e1 = -1; float p1 = -1.f;
#pragma unroll
    for (int e = 0; e < NE; ++e) {
      if (e == e0) continue;
      if (p[e] > p1) { p1 = p[e]; e1 = e; }
    }
    tsel[tok] = e0 | (e1 << 8);
    tp0[tok] = p0;
    tp1[tok] = p1;
  }
}

// ------- bucketize: DETERMINISTIC. one block per expert, prefix-scan slots -------
__global__ __launch_bounds__(1024) void bucketize_kernel(
    const int* __restrict__ tsel, const float* __restrict__ tp0,
    const float* __restrict__ tp1, int* __restrict__ cnt,
    int* __restrict__ btok, float* __restrict__ bp) {
  int e = blockIdx.x;
  int t = threadIdx.x;
  __shared__ int psum[1024];
  int sel[8], loc[8];
  int cntloc = 0;
  int base_tok = t * 8;
#pragma unroll
  for (int j = 0; j < 8; ++j) {
    int s = tsel[base_tok + j];
    int hit = ((s & 0xff) == e) ? 1 : ((((s >> 8) & 0xff) == e) ? 2 : 0);
    sel[j] = hit;
    loc[j] = cntloc;
    cntloc += (hit != 0);
  }
  psum[t] = cntloc;
  __syncthreads();
  for (int off = 1; off < 1024; off <<= 1) {
    int v = (t >= off) ? psum[t - off] : 0;
    __syncthreads();
    psum[t] += v;
    __syncthreads();
  }
  int excl = psum[t] - cntloc;
  if (t == 1023) cnt[e] = psum[1023];
#pragma unroll
  for (int j = 0; j < 8; ++j) {
    if (sel[j]) {
      int pos = excl + loc[j];
      int tok = base_tok + j;
      btok[e * N_TOK + pos] = tok;
      bp[e * N_TOK + pos] = (sel[j] == 1) ? tp0[tok] : tp1[tok];
    }
  }
}

// tt in 128-row tile units
__global__ void offsets_kernel(const int* __restrict__ cnt, int* __restrict__ offs,
                               int* __restrict__ tt) {
  if (threadIdx.x == 0) {
    int a = 0, b = 0;
    for (int e = 0; e < NE; ++e) {
      offs[e] = a; tt[e] = b;
      int pad = (cnt[e] + 127) & ~127;
      a += pad;
      b += pad >> 7;
    }
    offs[NE] = a; tt[NE] = b;
  }
}

// swizzled byte offset for (row, 16B-group) in [128][32] bf16 (64B rows)
__device__ __forceinline__ int swz_off(int row, int kg) {
  return row * 64 + ((kg ^ ((row >> 1) & 3)) * 16);
}

#define ROUTED_MAX 136   // ceil((16384+8*127)/128)
#define TAU1 (64 + ROUTED_MAX)  // 200

// ================ stage1: 128 rows x 128 B-rows (64 I-cols, G/U interleaved) ================
// m97-replica: 256 thr (4 waves, wave tile 64x64), 2-buf 32KB LDS, per tile:
// stage(z+1) -> read frags(z) -> 16 MFMA -> vmcnt(0)+barrier. 4 blocks/CU target.
__global__ __launch_bounds__(256, 4) void stage1_kernel(
    const bf16* __restrict__ xb, const bf16* __restrict__ wb1,
    const bf16* __restrict__ wb2, const int* __restrict__ cnt,
    const int* __restrict__ offs, const int* __restrict__ tt,
    const int* __restrict__ btok, bf16* __restrict__ H) {
  int bid = blockIdx.x;
  int wgid = (bid & 7) * 550 + (bid >> 3);   // 4400 = 8*550
  int tau = wgid % TAU1;
  int i0 = (wgid / TAU1) * 64;               // I-col base (22 slices)
  int e, row0, slotbase, limit;
  if (tau < 64) {
    e = NE; row0 = tau * 128; slotbase = 0; limit = N_TOK;
  } else {
    int tr = tau - 64;
    if (tr >= tt[NE]) return;
    e = NE - 1;
#pragma unroll
    for (int q = 0; q < NE; ++q) if (tr < tt[q + 1]) { e = q; break; }
    row0 = (tr - tt[e]) * 128;
    slotbase = N_TOK + offs[e];
    limit = cnt[e];
    if (row0 >= limit) return;
  }

  __shared__ __align__(16) char smem[32768];  // 2 bufs x (A 8K | B 8K)
  const int t = threadIdx.x;
  const int lane = t & 63, wid = t >> 6;
  const int wr = wid >> 1, wc = wid & 1;
  const int l15 = lane & 15, l4 = lane >> 4;

  // staging: thread loads A rows (srow, srow+64), B rows (srow, srow+64)
  const int srow = t >> 2;                        // 0..63
  const int gsrc = (t & 3) ^ ((srow >> 1) & 3);   // same for row+64 (64%4==0 in (row>>1)&3)
  int ar0 = row0 + srow, ar1 = row0 + srow + 64;
  int tok0, tok1;
  if (e == NE) { tok0 = ar0; tok1 = ar1; }
  else {
    int ix0 = e * N_TOK + (ar0 < N_TOK ? ar0 : N_TOK - 1);
    int ix1 = e * N_TOK + (ar1 < N_TOK ? ar1 : N_TOK - 1);
    tok0 = btok[ix0] & (N_TOK - 1);
    tok1 = btok[ix1] & (N_TOK - 1);
  }
  const bf16* asrc0 = xb + (size_t)tok0 * C_DIM + gsrc * 8;
  const bf16* asrc1 = xb + (size_t)tok1 * C_DIM + gsrc * 8;
  // B rows (G/U interleaved at 16-row granularity): row r -> q=r>>4, m=q>>1, sel=q&1
  const bf16* bsrc0;
  const bf16* bsrc1;
  {
    int r = srow;
    int q = r >> 4, m = q >> 1, sel = q & 1;
    int irow = i0 + m * 16 + (r & 15);
    bsrc0 = (sel ? wb2 : wb1) + ((size_t)e * I_DIM + irow) * C_DIM + gsrc * 8;
    r = srow + 64;
    q = r >> 4; m = q >> 1; sel = q & 1;
    irow = i0 + m * 16 + (r & 15);
    bsrc1 = (sel ? wb2 : wb1) + ((size_t)e * I_DIM + irow) * C_DIM + gsrc * 8;
  }
  const int lo0 = t * 16;
  const int NKT = C_DIM / 32;  // 32

  auto stAB = [&](int z) {
    if (z < NKT) {
      char* d = smem + (z & 1) * 16384;
      int k = z * 32;
      gload16(asrc0 + k, d + lo0);
      gload16(asrc1 + k, d + 4096 + lo0);
      gload16(bsrc0 + k, d + 8192 + lo0);
      gload16(bsrc1 + k, d + 12288 + lo0);
    }
  };

  int aoff[4], boff[4];
#pragma unroll
  for (int mf = 0; mf < 4; ++mf) aoff[mf] = swz_off(wr * 64 + mf * 16 + l15, l4);
#pragma unroll
  for (int nf = 0; nf < 4; ++nf) boff[nf] = 8192 + swz_off(wc * 64 + nf * 16 + l15, l4);

  f32x4 acc[4][4];
  f32x4 zero = {0.f, 0.f, 0.f, 0.f};
#pragma unroll
  for (int mf = 0; mf < 4; ++mf)
#pragma unroll
    for (int nf = 0; nf < 4; ++nf) acc[mf][nf] = zero;

  stAB(0);
  SCHED(); VM0(); BAR(); SCHED();

  for (int z = 0; z < NKT; ++z) {
    stAB(z + 1);
    char* base = smem + (z & 1) * 16384;
    bf16x8 av[4], bv[4];
#pragma unroll
    for (int mf = 0; mf < 4; ++mf) av[mf] = *(const bf16x8*)(base + aoff[mf]);
#pragma unroll
    for (int nf = 0; nf < 4; ++nf) bv[nf] = *(const bf16x8*)(base + boff[nf]);
    __builtin_amdgcn_s_setprio(1);
#pragma unroll
    for (int mf = 0; mf < 4; ++mf)
#pragma unroll
      for (int nf = 0; nf < 4; ++nf)
        acc[mf][nf] = __builtin_amdgcn_mfma_f32_16x16x32_bf16(av[mf], bv[nf], acc[mf][nf], 0, 0, 0);
    __builtin_amdgcn_s_setprio(0);
    SCHED(); VM0(); BAR(); SCHED();
  }

  // SwiGLU epilogue: nf pairs (0,1),(2,3) are (G,U) of the same 16 I-cols
#pragma unroll
  for (int mf = 0; mf < 4; ++mf)
#pragma unroll
    for (int r = 0; r < 4; ++r) {
      int rr = row0 + wr * 64 + mf * 16 + l4 * 4 + r;
      if (rr < limit) {
#pragma unroll
        for (int p = 0; p < 2; ++p) {
          float g = acc[mf][2 * p][r];
          float u = acc[mf][2 * p + 1][r];
          float h = (g / (1.f + __expf(-g))) * u;
          int col = i0 + (wc * 2 + p) * 16 + l15;
          H[(size_t)(slotbase + rr) * I_DIM + col] = (bf16)h;
        }
      }
    }
}

// ================ stage2: y (+)= p * (H W3^T), 128x128 ================
// SHARED=1: grid 512 = 8*64 (64 rowtiles x 8 ctiles), plain store, launched first.
// SHARED=0: grid 1088 = 8*136, atomicAdd, launched second (stream-ordered).
template <int SHARED>
__global__ __launch_bounds__(256, 4) void stage2_kernel(
    const bf16* __restrict__ H, const bf16* __restrict__ wb3,
    const int* __restrict__ cnt, const int* __restrict__ offs,
    const int* __restrict__ tt, const int* __restrict__ btok,
    const float* __restrict__ bp, float* __restrict__ y) {
  int bid = blockIdx.x;
  int e, row0, slotbase, limit, c0;
  if (SHARED) {
    int wgid = (bid & 7) * 64 + (bid >> 3);
    e = NE; row0 = (wgid % 64) * 128; slotbase = 0; limit = N_TOK;
    c0 = (wgid / 64) * 128;
  } else {
    int wgid = (bid & 7) * 136 + (bid >> 3);
    int tr = wgid % ROUTED_MAX;
    c0 = (wgid / ROUTED_MAX) * 128;
    if (tr >= tt[NE]) return;
    e = NE - 1;
#pragma unroll
    for (int q = 0; q < NE; ++q) if (tr < tt[q + 1]) { e = q; break; }
    row0 = (tr - tt[e]) * 128;
    slotbase = N_TOK + offs[e];
    limit = cnt[e];
    if (row0 >= limit) return;
  }

  __shared__ __align__(16) char smem[32768];
  const int t = threadIdx.x;
  const int lane = t & 63, wid = t >> 6;
  const int wr = wid >> 1, wc = wid & 1;
  const int l15 = lane & 15, l4 = lane >> 4;

  const int srow = t >> 2;
  const int gsrc = (t & 3) ^ ((srow >> 1) & 3);
  int sr0 = slotbase + row0 + srow;       if (sr0 > H_ROWS - 1) sr0 = H_ROWS - 1;
  int sr1 = slotbase + row0 + srow + 64;  if (sr1 > H_ROWS - 1) sr1 = H_ROWS - 1;
  const bf16* asrc0 = H + (size_t)sr0 * I_DIM + gsrc * 8;
  const bf16* asrc1 = H + (size_t)sr1 * I_DIM + gsrc * 8;
  const bf16* bsrc0 = wb3 + ((size_t)e * C_DIM + c0 + srow) * I_DIM + gsrc * 8;
  const bf16* bsrc1 = bsrc0 + (size_t)64 * I_DIM;
  const int lo0 = t * 16;
  const int NKT = I_DIM / 32;  // 44

  auto stAB = [&](int z) {
    if (z < NKT) {
      char* d = smem + (z & 1) * 16384;
      int k = z * 32;
      gload16(asrc0 + k, d + lo0);
      gload16(asrc1 + k, d + 4096 + lo0);
      gload16(bsrc0 + k, d + 8192 + lo0);
      gload16(bsrc1 + k, d + 12288 + lo0);
    }
  };

  int aoff[4], boff[4];
#pragma unroll
  for (int mf = 0; mf < 4; ++mf) aoff[mf] = swz_off(wr * 64 + mf * 16 + l15, l4);
#pragma unroll
  for (int nf = 0; nf < 4; ++nf) boff[nf] = 8192 + swz_off(wc * 64 + nf * 16 + l15, l4);

  f32x4 acc[4][4];
  f32x4 zero = {0.f, 0.f, 0.f, 0.f};
#pragma unroll
  for (int mf = 0; mf < 4; ++mf)
#pragma unroll
    for (int nf = 0; nf < 4; ++nf) acc[mf][nf] = zero;

  stAB(0);
  SCHED(); VM0(); BAR(); SCHED();

  for (int z = 0; z < NKT; ++z) {
    stAB(z + 1);
    char* base = smem + (z & 1) * 16384;
    bf16x8 av[4], bv[4];
#pragma unroll
    for (int mf = 0; mf < 4; ++mf) av[mf] = *(const bf16x8*)(base + aoff[mf]);
#pragma unroll
    for (int nf = 0; nf < 4; ++nf) bv[nf] = *(const bf16x8*)(base + boff[nf]);
    __builtin_amdgcn_s_setprio(1);
#pragma unroll
    for (int mf = 0; mf < 4; ++mf)
#pragma unroll
      for (int nf = 0; nf < 4; ++nf)
        acc[mf][nf] = __builtin_amdgcn_mfma_f32_16x16x32_bf16(av[mf], bv[nf], acc[mf][nf], 0, 0, 0);
    __builtin_amdgcn_s_setprio(0);
    SCHED(); VM0(); BAR(); SCHED();
  }

#pragma unroll
  for (int mf = 0; mf < 4; ++mf)
#pragma unroll
    for (int r = 0; r < 4; ++r) {
      int idx = row0 + wr * 64 + mf * 16 + l4 * 4 + r;
      if (idx < limit) {
        if (SHARED) {
#pragma unroll
          for (int nf = 0; nf < 4; ++nf) {
            int col = c0 + wc * 64 + nf * 16 + l15;
            y[(size_t)idx * C_DIM + col] = acc[mf][nf][r];
          }
        } else {
          float p = bp[e * N_TOK + idx];
          int tok = btok[e * N_TOK + idx] & (N_TOK - 1);
#pragma unroll
          for (int nf = 0; nf < 4; ++nf) {
            int col = c0 + wc * 64 + nf * 16 + l15;
            atomicAdd(&y[(size_t)tok * C_DIM + col], p * acc[mf][nf][r]);
          }
        }
      }
    }
}

extern "C" void kernel_launch(void* const* d_in, const int* in_sizes, int n_in,
                              void* d_out, int out_size, void* d_ws, size_t ws_size,
                              hipStream_t stream) {
  const float* x = (const float*)d_in[0];
  const float* Wg = (const float*)d_in[1];
  const float* W1 = (const float*)d_in[2];
  const float* W2 = (const float*)d_in[3];
  const float* W3 = (const float*)d_in[4];
  const float* Ws1 = (const float*)d_in[5];
  const float* Ws2 = (const float*)d_in[6];
  const float* Ws3 = (const float*)d_in[7];
  float* y = (float*)d_out;
  char* ws = (char*)d_ws;

  int* cnt = (int*)(ws + CNT_OFF);
  int* offs = (int*)(ws + OFFS_OFF);
  int* tt = (int*)(ws + TT_OFF);
  int* btok = (int*)(ws + BTOK_OFF);
  float* bp = (float*)(ws + BP_OFF);
  int* tsel = (int*)(ws + TSEL_OFF);
  float* tp0 = (float*)(ws + TP0_OFF);
  float* tp1 = (float*)(ws + TP1_OFF);
  bf16* xb = (bf16*)(ws + XB_OFF);
  bf16* wb1 = (bf16*)(ws + WB1_OFF);
  bf16* wb2 = (bf16*)(ws + WB2_OFF);
  bf16* wb3 = (bf16*)(ws + WB3_OFF);
  bf16* H = (bf16*)(ws + H_OFF);

  hipMemsetAsync(ws, 0, ROUTER_END, stream);

  auto conv = [&](const float* s, bf16* d, size_t n) {
    int n8 = (int)(n / 8);
    convert_kernel<<<(n8 + 255) / 256, 256, 0, stream>>>(s, d, n8);
  };
  conv(x, xb, (size_t)N_TOK * C_DIM);
  conv(W1, wb1, (size_t)NE * I_DIM * C_DIM);
  conv(Ws1, wb1 + (size_t)NE * I_DIM * C_DIM, (size_t)I_DIM * C_DIM);
  conv(W2, wb2, (size_t)NE * I_DIM * C_DIM);
  conv(Ws2, wb2 + (size_t)NE * I_DIM * C_DIM, (size_t)I_DIM * C_DIM);
  conv(W3, wb3, (size_t)NE * C_DIM * I_DIM);
  conv(Ws3, wb3 + (size_t)NE * C_DIM * I_DIM, (size_t)C_DIM * I_DIM);

  logits_kernel<<<N_TOK / 4, 256, 0, stream>>>(x, Wg, tsel, tp0, tp1);
  bucketize_kernel<<<NE, 1024, 0, stream>>>(tsel, tp0, tp1, cnt, btok, bp);
  offsets_kernel<<<1, 64, 0, stream>>>(cnt, offs, tt);

  stage1_kernel<<<TAU1 * 22, 256, 0, stream>>>(xb, wb1, wb2, cnt, offs, tt, btok, H);
  stage2_kernel<1><<<512, 256, 0, stream>>>(H, wb3, cnt, offs, tt, btok, bp, y);
  stage2_kernel<0><<<ROUTED_MAX * 8, 256, 0, stream>>>(H, wb3, cnt, offs, tt, btok, bp, y);
}

// Round 14
// 409.958 us; speedup vs baseline: 1.0017x; 1.0017x over previous
//
#include <hip/hip_runtime.h>
#include <stdint.h>

typedef __bf16 bf16;
typedef __attribute__((ext_vector_type(8))) __bf16 bf16x8;
typedef __attribute__((ext_vector_type(4))) float f32x4;

#define N_TOK 8192
#define C_DIM 1024
#define I_DIM 1408
#define NE 8
#define NEA 9
#define H_ROWS 25600

// ---- workspace byte offsets ----
#define CNT_OFF   0
#define OFFS_OFF  64
#define TT_OFF    128
#define BTOK_OFF  192
#define BP_OFF    (BTOK_OFF + NE * N_TOK * 4)
#define ROUTER_END (BP_OFF + NE * N_TOK * 4)
#define TSEL_OFF  ROUTER_END
#define TP0_OFF   (TSEL_OFF + N_TOK * 4)
#define TP1_OFF   (TP0_OFF + N_TOK * 4)
#define XB_OFF    (1u << 20)
#define WB1_OFF   (18u << 20)
#define WB2_OFF   (43u << 20)
#define WB3_OFF   (68u << 20)
#define H_OFF     (93u << 20)

__device__ __forceinline__ void gload16(const void* g, void* l) {
  __builtin_amdgcn_global_load_lds(
      (const __attribute__((address_space(1))) void*)g,
      (__attribute__((address_space(3))) void*)l, 16, 0, 0);
}

#define SCHED() __builtin_amdgcn_sched_barrier(0)
#define BAR()   __builtin_amdgcn_s_barrier()

__device__ __forceinline__ void vmw(int sel) {
  if (sel == 6) asm volatile("s_waitcnt vmcnt(6)" ::: "memory");
  else if (sel == 0) asm volatile("s_waitcnt vmcnt(0)" ::: "memory");
}

// m201-faithful phase: {4-8 ds_reads | 1 unit stage} -> bar -> lgkm0 -> 16 MFMA -> [vmcnt] -> bar
// BUF: 0/1 LDS dbuf; S: k-half (0/1); H_: M-half (0/1); READB: load bv this phase.
#define PH(BUF, S, H_, READB, STAGEBLK, VMSEL)                                 \
  {                                                                            \
    char* ab = smem + (BUF) * 65536 + (S) * 16384;                             \
    char* bb = smem + (BUF) * 65536 + 32768 + (S) * 16384;                     \
    if (READB) {                                                               \
      _Pragma("unroll") for (int nf = 0; nf < 4; ++nf)                         \
          bv[nf] = *(const bf16x8*)(bb + boff[nf]);                            \
    }                                                                          \
    _Pragma("unroll") for (int q = 0; q < 4; ++q)                              \
        av[q] = *(const bf16x8*)(ab + aoff[(H_)*4 + q]);                       \
    STAGEBLK;                                                                  \
    SCHED();                                                                   \
    BAR();                                                                     \
    asm volatile("s_waitcnt lgkmcnt(0)" ::: "memory");                         \
    SCHED();                                                                   \
    __builtin_amdgcn_s_setprio(1);                                             \
    _Pragma("unroll") for (int q = 0; q < 4; ++q)                              \
        _Pragma("unroll") for (int nf = 0; nf < 4; ++nf)                       \
            acc[(H_)*4 + q][nf] = __builtin_amdgcn_mfma_f32_16x16x32_bf16(     \
                av[q], bv[nf], acc[(H_)*4 + q][nf], 0, 0, 0);                  \
    __builtin_amdgcn_s_setprio(0);                                             \
    SCHED();                                                                   \
    vmw(VMSEL);                                                                \
    BAR();                                                                     \
    SCHED();                                                                   \
  }

// ---------------- conversion fp32 -> bf16 ----------------
__global__ __launch_bounds__(256) void convert_kernel(
    const float* __restrict__ src, bf16* __restrict__ dst, int n8) {
  int i = blockIdx.x * 256 + threadIdx.x;
  if (i >= n8) return;
  const float* s = src + (size_t)i * 8;
  float4 a = *(const float4*)(s);
  float4 b = *(const float4*)(s + 4);
  bf16x8 v;
  v[0] = (bf16)a.x; v[1] = (bf16)a.y; v[2] = (bf16)a.z; v[3] = (bf16)a.w;
  v[4] = (bf16)b.x; v[5] = (bf16)b.y; v[6] = (bf16)b.z; v[7] = (bf16)b.w;
  *(bf16x8*)(dst + (size_t)i * 8) = v;
}

// ---------------- logits: wave per token, top-2, NO atomics ----------------
__global__ __launch_bounds__(256) void logits_kernel(
    const float* __restrict__ x, const float* __restrict__ Wg,
    int* __restrict__ tsel, float* __restrict__ tp0, float* __restrict__ tp1) {
  __shared__ __align__(16) float wg[NE * C_DIM];
  int t = threadIdx.x;
#pragma unroll
  for (int j = 0; j < 8; ++j) {
    int idx = (t + 256 * j) * 4;
    *(float4*)&wg[idx] = *(const float4*)&Wg[idx];
  }
  __syncthreads();
  int wid = t >> 6, lane = t & 63;
  int tok = blockIdx.x * 4 + wid;
  const float* xr = x + (size_t)tok * C_DIM;
  float acc[NE];
#pragma unroll
  for (int e = 0; e < NE; ++e) acc[e] = 0.f;
#pragma unroll
  for (int j = 0; j < 4; ++j) {
    int c4 = (lane + 64 * j) * 4;
    float4 xv = *(const float4*)&xr[c4];
#pragma unroll
    for (int e = 0; e < NE; ++e) {
      float4 wv = *(const float4*)&wg[e * C_DIM + c4];
      acc[e] += xv.x * wv.x + xv.y * wv.y + xv.z * wv.z + xv.w * wv.w;
    }
  }
  for (int o = 32; o >= 1; o >>= 1)
#pragma unroll
    for (int e = 0; e < NE; ++e) acc[e] += __shfl_xor(acc[e], o, 64);
  if (lane == 0) {
    float m = acc[0];
#pragma unroll
    for (int e = 1; e < NE; ++e) m = fmaxf(m, acc[e]);
    float p[NE], s = 0.f;
#pragma unroll
    for (int e = 0; e < NE; ++e) { p[e] = __expf(acc[e] - m); s += p[e]; }
    float inv = 1.f / s;
#pragma unroll
    for (int e = 0; e < NE; ++e) p[e] *= inv;
    int e0 = 0; float p0 = p[0];
#pragma unroll
    for (int e = 1; e < NE; ++e) if (p[e] > p0) { p0 = p[e]; e0 = e; }
    int e1 = -1; float p1 = -1.f;
#pragma unroll
    for (int e = 0; e < NE; ++e) {
      if (e == e0) continue;
      if (p[e] > p1) { p1 = p[e]; e1 = e; }
    }
    tsel[tok] = e0 | (e1 << 8);
    tp0[tok] = p0;
    tp1[tok] = p1;
  }
}

// ------- bucketize: DETERMINISTIC. one block per expert, prefix-scan slots -------
__global__ __launch_bounds__(1024) void bucketize_kernel(
    const int* __restrict__ tsel, const float* __restrict__ tp0,
    const float* __restrict__ tp1, int* __restrict__ cnt,
    int* __restrict__ btok, float* __restrict__ bp) {
  int e = blockIdx.x;
  int t = threadIdx.x;
  __shared__ int psum[1024];
  int sel[8], loc[8];
  int cntloc = 0;
  int base_tok = t * 8;
#pragma unroll
  for (int j = 0; j < 8; ++j) {
    int s = tsel[base_tok + j];
    int hit = ((s & 0xff) == e) ? 1 : ((((s >> 8) & 0xff) == e) ? 2 : 0);
    sel[j] = hit;
    loc[j] = cntloc;
    cntloc += (hit != 0);
  }
  psum[t] = cntloc;
  __syncthreads();
  for (int off = 1; off < 1024; off <<= 1) {
    int v = (t >= off) ? psum[t - off] : 0;
    __syncthreads();
    psum[t] += v;
    __syncthreads();
  }
  int excl = psum[t] - cntloc;
  if (t == 1023) cnt[e] = psum[1023];
#pragma unroll
  for (int j = 0; j < 8; ++j) {
    if (sel[j]) {
      int pos = excl + loc[j];
      int tok = base_tok + j;
      btok[e * N_TOK + pos] = tok;
      bp[e * N_TOK + pos] = (sel[j] == 1) ? tp0[tok] : tp1[tok];
    }
  }
}

// tt in 256-row tile units
__global__ void offsets_kernel(const int* __restrict__ cnt, int* __restrict__ offs,
                               int* __restrict__ tt) {
  if (threadIdx.x == 0) {
    int a = 0, b = 0;
    for (int e = 0; e < NE; ++e) {
      offs[e] = a; tt[e] = b;
      int pad = (cnt[e] + 127) & ~127;
      a += pad;
      b += (pad + 255) >> 8;
    }
    offs[NE] = a; tt[NE] = b;
  }
}

// swizzled byte offset for (row, 16B-group) in a [256][32] bf16 unit (64B rows)
__device__ __forceinline__ int swz_off(int row, int kg) {
  return row * 64 + ((kg ^ ((row >> 1) & 3)) * 16);
}

// ================ stage1: 256 rows x 256 B-rows (128 I-cols, G/U interleaved) ================
// m201-faithful 8-phase engine: BK=64, LDS units {A0,A1,B0,B1} x 16KB x 2 dbuf = 128KB,
// one unit staged per phase, vmcnt(6) at ph4/ph8 (retire distance ~1 iter).
__global__ __launch_bounds__(512) void stage1_kernel(
    const bf16* __restrict__ xb, const bf16* __restrict__ wb1,
    const bf16* __restrict__ wb2, const int* __restrict__ cnt,
    const int* __restrict__ offs, const int* __restrict__ tt,
    const int* __restrict__ btok, bf16* __restrict__ H) {
  int bid = blockIdx.x;
  int wgid = (bid & 7) * 154 + (bid >> 3);
  int tau = wgid % 112;
  int i0 = (wgid / 112) * 128;
  int e, row0, slotbase, limit;
  if (tau < 32) {
    e = NE; row0 = tau * 256; slotbase = 0; limit = N_TOK;
  } else {
    int tr = tau - 32;
    if (tr >= tt[NE]) return;
    e = NE - 1;
#pragma unroll
    for (int q = 0; q < NE; ++q) if (tr < tt[q + 1]) { e = q; break; }
    row0 = (tr - tt[e]) * 256;
    slotbase = N_TOK + offs[e];
    limit = cnt[e];
    if (row0 >= limit) return;
  }

  __shared__ __align__(16) char smem[131072];
  const int t = threadIdx.x;
  const int lane = t & 63, wid = t >> 6;
  const int wr = wid >> 2, wc = wid & 3;
  const int l15 = lane & 15, l4 = lane >> 4;

  const int srow = t >> 2;
  const int gsrc = (t & 3) ^ ((srow >> 1) & 3);
  int ar0 = row0 + srow, ar1 = row0 + srow + 128;
  int tok0, tok1;
  if (e == NE) { tok0 = ar0; tok1 = ar1; }
  else {
    int ix0 = e * N_TOK + (ar0 < N_TOK ? ar0 : N_TOK - 1);
    int ix1 = e * N_TOK + (ar1 < N_TOK ? ar1 : N_TOK - 1);
    tok0 = btok[ix0] & (N_TOK - 1);
    tok1 = btok[ix1] & (N_TOK - 1);
  }
  const bf16* asrc0 = xb + (size_t)tok0 * C_DIM + gsrc * 8;
  const bf16* asrc1 = xb + (size_t)tok1 * C_DIM + gsrc * 8;
  // B rows (G/U interleaved at 16-row granularity over 256 rows)
  const bf16* bsrc0;
  const bf16* bsrc1;
  {
    int r = srow;
    int q = r >> 4, m = q >> 1, sel = q & 1;
    int irow = i0 + m * 16 + (r & 15);
    bsrc0 = (sel ? wb2 : wb1) + ((size_t)e * I_DIM + irow) * C_DIM + gsrc * 8;
    r = srow + 128;
    q = r >> 4; m = q >> 1; sel = q & 1;
    irow = i0 + m * 16 + (r & 15);
    bsrc1 = (sel ? wb2 : wb1) + ((size_t)e * I_DIM + irow) * C_DIM + gsrc * 8;
  }
  const int lo0 = t * 16;
  const int NKT = C_DIM / 64;  // 16 K64-steps

  // unit stages: z = K64-step; slots A0=0,A1=1,B0=2,B1=3; 2 gloads each
  auto stA = [&](int z, int s) {
    if (z < NKT) {
      char* d = smem + (z & 1) * 65536 + s * 16384;
      int k = z * 64 + s * 32;
      gload16(asrc0 + k, d + lo0);
      gload16(asrc1 + k, d + 8192 + lo0);
    }
  };
  auto stB = [&](int z, int s) {
    if (z < NKT) {
      char* d = smem + (z & 1) * 65536 + 32768 + s * 16384;
      int k = z * 64 + s * 32;
      gload16(bsrc0 + k, d + lo0);
      gload16(bsrc1 + k, d + 8192 + lo0);
    }
  };

  int aoff[8], boff[4];
#pragma unroll
  for (int mf = 0; mf < 8; ++mf) aoff[mf] = swz_off(wr * 128 + mf * 16 + l15, l4);
#pragma unroll
  for (int nf = 0; nf < 4; ++nf) boff[nf] = swz_off(wc * 64 + nf * 16 + l15, l4);

  f32x4 acc[8][4];
  f32x4 zero = {0.f, 0.f, 0.f, 0.f};
#pragma unroll
  for (int mf = 0; mf < 8; ++mf)
#pragma unroll
    for (int nf = 0; nf < 4; ++nf) acc[mf][nf] = zero;
  bf16x8 av[4], bv[4];

  // prologue: T0 {B0,A0,B1,A1} + T1 {B0,A0,B1} = 14 loads; vmcnt(6) retires T0's 8
  stB(0, 0); stA(0, 0); stB(0, 1); stA(0, 1);
  stB(1, 0); stA(1, 0); stB(1, 1);
  SCHED();
  asm volatile("s_waitcnt vmcnt(6)" ::: "memory");
  BAR(); SCHED();

  const int NIT = NKT / 2;  // 8
  for (int it = 0; it < NIT; ++it) {
    int T1z = 2 * it + 1, T2z = 2 * it + 2, T3z = 2 * it + 3;
    int vm4 = (it == NIT - 1) ? 0 : 6;
    int vm8 = (it == NIT - 1) ? -1 : 6;
    PH(0, 0, 0, 1, { stA(T1z, 1); }, -1);   // ph1
    PH(0, 0, 1, 0, { stB(T2z, 0); }, -1);   // ph2
    PH(0, 1, 0, 1, { stA(T2z, 0); }, -1);   // ph3
    PH(0, 1, 1, 0, { stB(T2z, 1); }, vm4);  // ph4
    PH(1, 0, 0, 1, { stA(T2z, 1); }, -1);   // ph5
    PH(1, 0, 1, 0, { stB(T3z, 0); }, -1);   // ph6
    PH(1, 1, 0, 1, { stA(T3z, 0); }, -1);   // ph7
    PH(1, 1, 1, 0, { stB(T3z, 1); }, vm8);  // ph8
  }
  asm volatile("s_waitcnt vmcnt(0)" ::: "memory");

  // SwiGLU epilogue: nf pairs (0,1),(2,3) are (G,U) of the same 16 I-cols
#pragma unroll
  for (int mf = 0; mf < 8; ++mf)
#pragma unroll
    for (int r = 0; r < 4; ++r) {
      int rr = row0 + wr * 128 + mf * 16 + l4 * 4 + r;
      if (rr < limit) {
#pragma unroll
        for (int p = 0; p < 2; ++p) {
          float g = acc[mf][2 * p][r];
          float u = acc[mf][2 * p + 1][r];
          float h = (g / (1.f + __expf(-g))) * u;
          int col = i0 + (wc * 2 + p) * 16 + l15;
          H[(size_t)(slotbase + rr) * I_DIM + col] = (bf16)h;
        }
      }
    }
}

// ================ stage2: y (+)= p * (H W3^T), 256x256, same 8-phase engine ================
template <int SHARED>
__global__ __launch_bounds__(512) void stage2_kernel(
    const bf16* __restrict__ H, const bf16* __restrict__ wb3,
    const int* __restrict__ cnt, const int* __restrict__ offs,
    const int* __restrict__ tt, const int* __restrict__ btok,
    const float* __restrict__ bp, float* __restrict__ y) {
  int bid = blockIdx.x;
  int e, row0, slotbase, limit, c0;
  if (SHARED) {
    int wgid = (bid & 7) * 16 + (bid >> 3);
    e = NE; row0 = (wgid % 32) * 256; slotbase = 0; limit = N_TOK;
    c0 = (wgid / 32) * 256;
  } else {
    int wgid = (bid & 7) * 40 + (bid >> 3);
    int tr = wgid % 80;
    c0 = (wgid / 80) * 256;
    if (tr >= tt[NE]) return;
    e = NE - 1;
#pragma unroll
    for (int q = 0; q < NE; ++q) if (tr < tt[q + 1]) { e = q; break; }
    row0 = (tr - tt[e]) * 256;
    slotbase = N_TOK + offs[e];
    limit = cnt[e];
    if (row0 >= limit) return;
  }

  __shared__ __align__(16) char smem[131072];
  const int t = threadIdx.x;
  const int lane = t & 63, wid = t >> 6;
  const int wr = wid >> 2, wc = wid & 3;
  const int l15 = lane & 15, l4 = lane >> 4;

  const int srow = t >> 2;
  const int gsrc = (t & 3) ^ ((srow >> 1) & 3);
  int sr0 = slotbase + row0 + srow;        if (sr0 > H_ROWS - 1) sr0 = H_ROWS - 1;
  int sr1 = slotbase + row0 + srow + 128;  if (sr1 > H_ROWS - 1) sr1 = H_ROWS - 1;
  const bf16* asrc0 = H + (size_t)sr0 * I_DIM + gsrc * 8;
  const bf16* asrc1 = H + (size_t)sr1 * I_DIM + gsrc * 8;
  const bf16* bsrc0 = wb3 + ((size_t)e * C_DIM + c0 + srow) * I_DIM + gsrc * 8;
  const bf16* bsrc1 = bsrc0 + (size_t)128 * I_DIM;
  const int lo0 = t * 16;
  const int NKT = I_DIM / 64;  // 22

  auto stA = [&](int z, int s) {
    if (z < NKT) {
      char* d = smem + (z & 1) * 65536 + s * 16384;
      int k = z * 64 + s * 32;
      gload16(asrc0 + k, d + lo0);
      gload16(asrc1 + k, d + 8192 + lo0);
    }
  };
  auto stB = [&](int z, int s) {
    if (z < NKT) {
      char* d = smem + (z & 1) * 65536 + 32768 + s * 16384;
      int k = z * 64 + s * 32;
      gload16(bsrc0 + k, d + lo0);
      gload16(bsrc1 + k, d + 8192 + lo0);
    }
  };

  int aoff[8], boff[4];
#pragma unroll
  for (int mf = 0; mf < 8; ++mf) aoff[mf] = swz_off(wr * 128 + mf * 16 + l15, l4);
#pragma unroll
  for (int nf = 0; nf < 4; ++nf) boff[nf] = swz_off(wc * 64 + nf * 16 + l15, l4);

  f32x4 acc[8][4];
  f32x4 zero = {0.f, 0.f, 0.f, 0.f};
#pragma unroll
  for (int mf = 0; mf < 8; ++mf)
#pragma unroll
    for (int nf = 0; nf < 4; ++nf) acc[mf][nf] = zero;
  bf16x8 av[4], bv[4];

  stB(0, 0); stA(0, 0); stB(0, 1); stA(0, 1);
  stB(1, 0); stA(1, 0); stB(1, 1);
  SCHED();
  asm volatile("s_waitcnt vmcnt(6)" ::: "memory");
  BAR(); SCHED();

  const int NIT = NKT / 2;  // 11
  for (int it = 0; it < NIT; ++it) {
    int T1z = 2 * it + 1, T2z = 2 * it + 2, T3z = 2 * it + 3;
    int vm4 = (it == NIT - 1) ? 0 : 6;
    int vm8 = (it == NIT - 1) ? -1 : 6;
    PH(0, 0, 0, 1, { stA(T1z, 1); }, -1);
    PH(0, 0, 1, 0, { stB(T2z, 0); }, -1);
    PH(0, 1, 0, 1, { stA(T2z, 0); }, -1);
    PH(0, 1, 1, 0, { stB(T2z, 1); }, vm4);
    PH(1, 0, 0, 1, { stA(T2z, 1); }, -1);
    PH(1, 0, 1, 0, { stB(T3z, 0); }, -1);
    PH(1, 1, 0, 1, { stA(T3z, 0); }, -1);
    PH(1, 1, 1, 0, { stB(T3z, 1); }, vm8);
  }
  asm volatile("s_waitcnt vmcnt(0)" ::: "memory");

#pragma unroll
  for (int mf = 0; mf < 8; ++mf)
#pragma unroll
    for (int r = 0; r < 4; ++r) {
      int idx = row0 + wr * 128 + mf * 16 + l4 * 4 + r;
      if (idx < limit) {
        if (SHARED) {
#pragma unroll
          for (int nf = 0; nf < 4; ++nf) {
            int col = c0 + wc * 64 + nf * 16 + l15;
            y[(size_t)idx * C_DIM + col] = acc[mf][nf][r];
          }
        } else {
          float p = bp[e * N_TOK + idx];
          int tok = btok[e * N_TOK + idx] & (N_TOK - 1);
#pragma unroll
          for (int nf = 0; nf < 4; ++nf) {
            int col = c0 + wc * 64 + nf * 16 + l15;
            atomicAdd(&y[(size_t)tok * C_DIM + col], p * acc[mf][nf][r]);
          }
        }
      }
    }
}

extern "C" void kernel_launch(void* const* d_in, const int* in_sizes, int n_in,
                              void* d_out, int out_size, void* d_ws, size_t ws_size,
                              hipStream_t stream) {
  const float* x = (const float*)d_in[0];
  const float* Wg = (const float*)d_in[1];
  const float* W1 = (const float*)d_in[2];
  const float* W2 = (const float*)d_in[3];
  const float* W3 = (const float*)d_in[4];
  const float* Ws1 = (const float*)d_in[5];
  const float* Ws2 = (const float*)d_in[6];
  const float* Ws3 = (const float*)d_in[7];
  float* y = (float*)d_out;
  char* ws = (char*)d_ws;

  int* cnt = (int*)(ws + CNT_OFF);
  int* offs = (int*)(ws + OFFS_OFF);
  int* tt = (int*)(ws + TT_OFF);
  int* btok = (int*)(ws + BTOK_OFF);
  float* bp = (float*)(ws + BP_OFF);
  int* tsel = (int*)(ws + TSEL_OFF);
  float* tp0 = (float*)(ws + TP0_OFF);
  float* tp1 = (float*)(ws + TP1_OFF);
  bf16* xb = (bf16*)(ws + XB_OFF);
  bf16* wb1 = (bf16*)(ws + WB1_OFF);
  bf16* wb2 = (bf16*)(ws + WB2_OFF);
  bf16* wb3 = (bf16*)(ws + WB3_OFF);
  bf16* H = (bf16*)(ws + H_OFF);

  hipMemsetAsync(ws, 0, ROUTER_END, stream);

  auto conv = [&](const float* s, bf16* d, size_t n) {
    int n8 = (int)(n / 8);
    convert_kernel<<<(n8 + 255) / 256, 256, 0, stream>>>(s, d, n8);
  };
  conv(x, xb, (size_t)N_TOK * C_DIM);
  conv(W1, wb1, (size_t)NE * I_DIM * C_DIM);
  conv(Ws1, wb1 + (size_t)NE * I_DIM * C_DIM, (size_t)I_DIM * C_DIM);
  conv(W2, wb2, (size_t)NE * I_DIM * C_DIM);
  conv(Ws2, wb2 + (size_t)NE * I_DIM * C_DIM, (size_t)I_DIM * C_DIM);
  conv(W3, wb3, (size_t)NE * C_DIM * I_DIM);
  conv(Ws3, wb3 + (size_t)NE * C_DIM * I_DIM, (size_t)C_DIM * I_DIM);

  logits_kernel<<<N_TOK / 4, 256, 0, stream>>>(x, Wg, tsel, tp0, tp1);
  bucketize_kernel<<<NE, 1024, 0, stream>>>(tsel, tp0, tp1, cnt, btok, bp);
  offsets_kernel<<<1, 64, 0, stream>>>(cnt, offs, tt);

  stage1_kernel<<<1232, 512, 0, stream>>>(xb, wb1, wb2, cnt, offs, tt, btok, H);
  stage2_kernel<1><<<128, 512, 0, stream>>>(H, wb3, cnt, offs, tt, btok, bp, y);
  stage2_kernel<0><<<320, 512, 0, stream>>>(H, wb3, cnt, offs, tt, btok, bp, y);
}

// Round 15
// 383.647 us; speedup vs baseline: 1.0704x; 1.0686x over previous
//
#include <hip/hip_runtime.h>
#include <stdint.h>

typedef __bf16 bf16;
typedef __attribute__((ext_vector_type(8))) __bf16 bf16x8;
typedef __attribute__((ext_vector_type(4))) float f32x4;

#define N_TOK 8192
#define C_DIM 1024
#define I_DIM 1408
#define NE 8
#define NEA 9
#define H_ROWS 25600

// ---- workspace byte offsets ----
#define CNT_OFF   0
#define OFFS_OFF  64
#define TT_OFF    128
#define BTOK_OFF  192
#define BP_OFF    (BTOK_OFF + NE * N_TOK * 4)
#define ROUTER_END (BP_OFF + NE * N_TOK * 4)
#define TSEL_OFF  ROUTER_END
#define TP0_OFF   (TSEL_OFF + N_TOK * 4)
#define TP1_OFF   (TP0_OFF + N_TOK * 4)
#define XB_OFF    (1u << 20)
#define WB1_OFF   (18u << 20)
#define WB2_OFF   (43u << 20)
#define WB3_OFF   (68u << 20)
#define H_OFF     (93u << 20)

__device__ __forceinline__ void gload16(const void* g, void* l) {
  __builtin_amdgcn_global_load_lds(
      (const __attribute__((address_space(1))) void*)g,
      (__attribute__((address_space(3))) void*)l, 16, 0, 0);
}

#define SCHED() __builtin_amdgcn_sched_barrier(0)
#define BAR()   __builtin_amdgcn_s_barrier()
#define VM6()   asm volatile("s_waitcnt vmcnt(6)" ::: "memory")
#define VM0()   asm volatile("s_waitcnt vmcnt(0)" ::: "memory")

// MFMA cluster: acc[H*4+q][nf] += AV[q] * BV[nf]; H is a literal.
#define MM(AV, BV, H)                                                          \
  {                                                                            \
    __builtin_amdgcn_s_setprio(1);                                             \
    _Pragma("unroll") for (int q = 0; q < 4; ++q)                              \
        _Pragma("unroll") for (int nf = 0; nf < 4; ++nf)                       \
            acc[(H)*4 + q][nf] = __builtin_amdgcn_mfma_f32_16x16x32_bf16(      \
                AV[q], BV[nf], acc[(H)*4 + q][nf], 0, 0, 0);                   \
    __builtin_amdgcn_s_setprio(0);                                             \
  }

// ---------------- merged conversion fp32 -> bf16 (all 7 segments, 1 launch) ----------------
// segment n8 sizes (compile-time): x 1048576 | W1 1441792 | Ws1 180224 | W2 1441792
// | Ws2 180224 | W3 1441792 | Ws3 180224; total 5914624
#define C0 1048576
#define C1 (C0 + 1441792)
#define C2 (C1 + 180224)
#define C3 (C2 + 1441792)
#define C4 (C3 + 180224)
#define C5 (C4 + 1441792)
#define C6 (C5 + 180224)

__global__ __launch_bounds__(256) void convert_all_kernel(
    const float* __restrict__ x, const float* __restrict__ W1,
    const float* __restrict__ Ws1, const float* __restrict__ W2,
    const float* __restrict__ Ws2, const float* __restrict__ W3,
    const float* __restrict__ Ws3, char* __restrict__ ws) {
  for (int i = blockIdx.x * 256 + threadIdx.x; i < C6; i += gridDim.x * 256) {
    const float* s;
    bf16* d;
    size_t off;
    if (i < C0) {
      s = x; d = (bf16*)(ws + XB_OFF); off = i;
    } else if (i < C1) {
      s = W1; d = (bf16*)(ws + WB1_OFF); off = i - C0;
    } else if (i < C2) {
      s = Ws1; d = (bf16*)(ws + WB1_OFF) + (size_t)NE * I_DIM * C_DIM; off = i - C1;
    } else if (i < C3) {
      s = W2; d = (bf16*)(ws + WB2_OFF); off = i - C2;
    } else if (i < C4) {
      s = Ws2; d = (bf16*)(ws + WB2_OFF) + (size_t)NE * I_DIM * C_DIM; off = i - C3;
    } else if (i < C5) {
      s = W3; d = (bf16*)(ws + WB3_OFF); off = i - C4;
    } else {
      s = Ws3; d = (bf16*)(ws + WB3_OFF) + (size_t)NE * C_DIM * I_DIM; off = i - C5;
    }
    const float* sp = s + off * 8;
    float4 a = *(const float4*)(sp);
    float4 b = *(const float4*)(sp + 4);
    bf16x8 v;
    v[0] = (bf16)a.x; v[1] = (bf16)a.y; v[2] = (bf16)a.z; v[3] = (bf16)a.w;
    v[4] = (bf16)b.x; v[5] = (bf16)b.y; v[6] = (bf16)b.z; v[7] = (bf16)b.w;
    *(bf16x8*)(d + off * 8) = v;
  }
}

// ---------------- logits: wave per token, top-2, NO atomics ----------------
__global__ __launch_bounds__(256) void logits_kernel(
    const float* __restrict__ x, const float* __restrict__ Wg,
    int* __restrict__ tsel, float* __restrict__ tp0, float* __restrict__ tp1) {
  __shared__ __align__(16) float wg[NE * C_DIM];
  int t = threadIdx.x;
#pragma unroll
  for (int j = 0; j < 8; ++j) {
    int idx = (t + 256 * j) * 4;
    *(float4*)&wg[idx] = *(const float4*)&Wg[idx];
  }
  __syncthreads();
  int wid = t >> 6, lane = t & 63;
  int tok = blockIdx.x * 4 + wid;
  const float* xr = x + (size_t)tok * C_DIM;
  float acc[NE];
#pragma unroll
  for (int e = 0; e < NE; ++e) acc[e] = 0.f;
#pragma unroll
  for (int j = 0; j < 4; ++j) {
    int c4 = (lane + 64 * j) * 4;
    float4 xv = *(const float4*)&xr[c4];
#pragma unroll
    for (int e = 0; e < NE; ++e) {
      float4 wv = *(const float4*)&wg[e * C_DIM + c4];
      acc[e] += xv.x * wv.x + xv.y * wv.y + xv.z * wv.z + xv.w * wv.w;
    }
  }
  for (int o = 32; o >= 1; o >>= 1)
#pragma unroll
    for (int e = 0; e < NE; ++e) acc[e] += __shfl_xor(acc[e], o, 64);
  if (lane == 0) {
    float m = acc[0];
#pragma unroll
    for (int e = 1; e < NE; ++e) m = fmaxf(m, acc[e]);
    float p[NE], s = 0.f;
#pragma unroll
    for (int e = 0; e < NE; ++e) { p[e] = __expf(acc[e] - m); s += p[e]; }
    float inv = 1.f / s;
#pragma unroll
    for (int e = 0; e < NE; ++e) p[e] *= inv;
    int e0 = 0; float p0 = p[0];
#pragma unroll
    for (int e = 1; e < NE; ++e) if (p[e] > p0) { p0 = p[e]; e0 = e; }
    int e1 = -1; float p1 = -1.f;
#pragma unroll
    for (int e = 0; e < NE; ++e) {
      if (e == e0) continue;
      if (p[e] > p1) { p1 = p[e]; e1 = e; }
    }
    tsel[tok] = e0 | (e1 << 8);
    tp0[tok] = p0;
    tp1[tok] = p1;
  }
}

// ------- bucketize: DETERMINISTIC. one block per expert, prefix-scan slots -------
__global__ __launch_bounds__(1024) void bucketize_kernel(
    const int* __restrict__ tsel, const float* __restrict__ tp0,
    const float* __restrict__ tp1, int* __restrict__ cnt,
    int* __restrict__ btok, float* __restrict__ bp) {
  int e = blockIdx.x;
  int t = threadIdx.x;
  __shared__ int psum[1024];
  int sel[8], loc[8];
  int cntloc = 0;
  int base_tok = t * 8;
#pragma unroll
  for (int j = 0; j < 8; ++j) {
    int s = tsel[base_tok + j];
    int hit = ((s & 0xff) == e) ? 1 : ((((s >> 8) & 0xff) == e) ? 2 : 0);
    sel[j] = hit;
    loc[j] = cntloc;
    cntloc += (hit != 0);
  }
  psum[t] = cntloc;
  __syncthreads();
  for (int off = 1; off < 1024; off <<= 1) {
    int v = (t >= off) ? psum[t - off] : 0;
    __syncthreads();
    psum[t] += v;
    __syncthreads();
  }
  int excl = psum[t] - cntloc;
  if (t == 1023) cnt[e] = psum[1023];
#pragma unroll
  for (int j = 0; j < 8; ++j) {
    if (sel[j]) {
      int pos = excl + loc[j];
      int tok = base_tok + j;
      btok[e * N_TOK + pos] = tok;
      bp[e * N_TOK + pos] = (sel[j] == 1) ? tp0[tok] : tp1[tok];
    }
  }
}

__global__ void offsets_kernel(const int* __restrict__ cnt, int* __restrict__ offs,
                               int* __restrict__ tt) {
  if (threadIdx.x == 0) {
    int a = 0, b = 0;
    for (int e = 0; e < NE; ++e) {
      offs[e] = a; tt[e] = b;
      int pad = (cnt[e] + 127) & ~127;
      a += pad;
      b += (pad + 255) >> 8;
    }
    offs[NE] = a; tt[NE] = b;
  }
}

// swizzled byte offset for (row, 16B-group) in [256][32] bf16 (64B rows)
__device__ __forceinline__ int swz_off(int row, int kg) {
  return row * 64 + ((kg ^ ((row >> 1) & 3)) * 16);
}

// ================ stage1: 256 rows x 128 I-cols (G/U interleaved B) ================
// R11 engine (best measured): reg-dbuf pipelined phases, 4-buf BK32, vmcnt(6).
__global__ __launch_bounds__(512) void stage1_kernel(
    const bf16* __restrict__ xb, const bf16* __restrict__ wb1,
    const bf16* __restrict__ wb2, const int* __restrict__ cnt,
    const int* __restrict__ offs, const int* __restrict__ tt,
    const int* __restrict__ btok, bf16* __restrict__ H) {
  int bid = blockIdx.x;
  int wgid = (bid & 7) * 154 + (bid >> 3);
  int tau = wgid % 112;
  int i0 = (wgid / 112) * 128;
  int e, row0, slotbase, limit;
  if (tau < 32) {
    e = NE; row0 = tau * 256; slotbase = 0; limit = N_TOK;
  } else {
    int tr = tau - 32;
    if (tr >= tt[NE]) return;
    e = NE - 1;
#pragma unroll
    for (int q = 0; q < NE; ++q) if (tr < tt[q + 1]) { e = q; break; }
    row0 = (tr - tt[e]) * 256;
    slotbase = N_TOK + offs[e];
    limit = cnt[e];
    if (row0 >= limit) return;
  }

  __shared__ __align__(16) char smem[131072];  // 4 bufs x (A 16K | B 16K)
  const int t = threadIdx.x;
  const int lane = t & 63, wid = t >> 6;
  const int wr = wid >> 2, wc = wid & 3;
  const int l15 = lane & 15, l4 = lane >> 4;

  const int srow = t >> 2;
  const int gsrc = (t & 3) ^ ((srow >> 1) & 3);
  int ar0 = row0 + srow, ar1 = row0 + srow + 128;
  int tok0, tok1;
  if (e == NE) { tok0 = ar0; tok1 = ar1; }
  else {
    int ix0 = e * N_TOK + (ar0 < N_TOK ? ar0 : N_TOK - 1);
    int ix1 = e * N_TOK + (ar1 < N_TOK ? ar1 : N_TOK - 1);
    tok0 = btok[ix0] & (N_TOK - 1);
    tok1 = btok[ix1] & (N_TOK - 1);
  }
  const bf16* asrc0 = xb + (size_t)tok0 * C_DIM + gsrc * 8;
  const bf16* asrc1 = xb + (size_t)tok1 * C_DIM + gsrc * 8;
  const bf16* bsrc0;
  const bf16* bsrc1;
  {
    int r = srow;
    int q = r >> 4, m = q >> 1, sel = q & 1;
    int irow = i0 + m * 16 + (r & 15);
    bsrc0 = (sel ? wb2 : wb1) + ((size_t)e * I_DIM + irow) * C_DIM + gsrc * 8;
    r = srow + 128;
    q = r >> 4; m = q >> 1; sel = q & 1;
    irow = i0 + m * 16 + (r & 15);
    bsrc1 = (sel ? wb2 : wb1) + ((size_t)e * I_DIM + irow) * C_DIM + gsrc * 8;
  }
  const int lo0 = t * 16;
  const int NKT = C_DIM / 32;  // 32

  auto stA = [&](int z) {
    if (z < NKT) {
      char* d = smem + (z & 3) * 32768;
      int k = z * 32;
      gload16(asrc0 + k, d + lo0);
      gload16(asrc1 + k, d + 8192 + lo0);
    }
  };
  auto stB = [&](int z) {
    if (z < NKT) {
      char* d = smem + (z & 3) * 32768 + 16384;
      int k = z * 32;
      gload16(bsrc0 + k, d + lo0);
      gload16(bsrc1 + k, d + 8192 + lo0);
    }
  };

  int aoff[8], boff[4];
#pragma unroll
  for (int mf = 0; mf < 8; ++mf) aoff[mf] = swz_off(wr * 128 + mf * 16 + l15, l4);
#pragma unroll
  for (int nf = 0; nf < 4; ++nf) boff[nf] = swz_off(wc * 64 + nf * 16 + l15, l4);

  f32x4 acc[8][4];
  f32x4 zero = {0.f, 0.f, 0.f, 0.f};
#pragma unroll
  for (int mf = 0; mf < 8; ++mf)
#pragma unroll
    for (int nf = 0; nf < 4; ++nf) acc[mf][nf] = zero;

  bf16x8 av0[4], av1[4], bv0[4], bv1[4];
  auto rdA = [&](bf16x8* dst, int T, int h) {
    char* base = smem + (T & 3) * 32768;
#pragma unroll
    for (int q = 0; q < 4; ++q) dst[q] = *(const bf16x8*)(base + aoff[h * 4 + q]);
  };
  auto rdB = [&](bf16x8* dst, int T) {
    char* base = smem + (T & 3) * 32768 + 16384;
#pragma unroll
    for (int nf = 0; nf < 4; ++nf) dst[nf] = *(const bf16x8*)(base + boff[nf]);
  };

  stB(0); stA(0); stB(1); stA(1); stB(2); stA(2);
  VM0();
  BAR();
  SCHED();
  rdA(av0, 0, 0); rdB(bv0, 0);

  const int NIT = NKT / 2;  // 16
  for (int it = 0; it < NIT; ++it) {
    int T0 = 2 * it, T1 = 2 * it + 1, T2n = 2 * it + 2;
    int zB = 2 * it + 3, zC = 2 * it + 4;
    rdA(av1, T0, 1);
    MM(av0, bv0, 0);
    stB(zB);
    SCHED(); VM6(); BAR(); SCHED();
    rdA(av0, T1, 0); rdB(bv1, T1);
    MM(av1, bv0, 1);
    stA(zB);
    SCHED(); BAR(); SCHED();
    rdA(av1, T1, 1);
    MM(av0, bv1, 0);
    stB(zC);
    SCHED(); VM6(); BAR(); SCHED();
    if (it + 1 < NIT) { rdA(av0, T2n, 0); rdB(bv0, T2n); }
    MM(av1, bv1, 1);
    stA(zC);
    SCHED(); BAR(); SCHED();
  }
  VM0();

#pragma unroll
  for (int mf = 0; mf < 8; ++mf)
#pragma unroll
    for (int r = 0; r < 4; ++r) {
      int rr = row0 + wr * 128 + mf * 16 + l4 * 4 + r;
      if (rr < limit) {
#pragma unroll
        for (int p = 0; p < 2; ++p) {
          float g = acc[mf][2 * p][r];
          float u = acc[mf][2 * p + 1][r];
          float h = (g / (1.f + __expf(-g))) * u;
          int col = i0 + (wc * 2 + p) * 16 + l15;
          H[(size_t)(slotbase + rr) * I_DIM + col] = (bf16)h;
        }
      }
    }
}

// ================ stage2: y += p * (H W3^T), 256x256, ONE all-atomic launch ================
// y pre-zeroed via hipMemsetAsync. Grid 448 = 8*56: wgid<128 shared, else routed.
__global__ __launch_bounds__(512) void stage2_kernel(
    const bf16* __restrict__ H, const bf16* __restrict__ wb3,
    const int* __restrict__ cnt, const int* __restrict__ offs,
    const int* __restrict__ tt, const int* __restrict__ btok,
    const float* __restrict__ bp, float* __restrict__ y) {
  int bid = blockIdx.x;
  int wgid = (bid & 7) * 56 + (bid >> 3);
  int e, row0, slotbase, limit, c0;
  if (wgid < 128) {
    e = NE; row0 = (wgid % 32) * 256; slotbase = 0; limit = N_TOK;
    c0 = (wgid / 32) * 256;
  } else {
    int r = wgid - 128;
    int tr = r % 80;
    c0 = (r / 80) * 256;
    if (tr >= tt[NE]) return;
    e = NE - 1;
#pragma unroll
    for (int q = 0; q < NE; ++q) if (tr < tt[q + 1]) { e = q; break; }
    row0 = (tr - tt[e]) * 256;
    slotbase = N_TOK + offs[e];
    limit = cnt[e];
    if (row0 >= limit) return;
  }

  __shared__ __align__(16) char smem[131072];
  const int t = threadIdx.x;
  const int lane = t & 63, wid = t >> 6;
  const int wr = wid >> 2, wc = wid & 3;
  const int l15 = lane & 15, l4 = lane >> 4;

  const int srow = t >> 2;
  const int gsrc = (t & 3) ^ ((srow >> 1) & 3);
  int sr0 = slotbase + row0 + srow;        if (sr0 > H_ROWS - 1) sr0 = H_ROWS - 1;
  int sr1 = slotbase + row0 + srow + 128;  if (sr1 > H_ROWS - 1) sr1 = H_ROWS - 1;
  const bf16* asrc0 = H + (size_t)sr0 * I_DIM + gsrc * 8;
  const bf16* asrc1 = H + (size_t)sr1 * I_DIM + gsrc * 8;
  const bf16* bsrc0 = wb3 + ((size_t)e * C_DIM + c0 + srow) * I_DIM + gsrc * 8;
  const bf16* bsrc1 = bsrc0 + (size_t)128 * I_DIM;
  const int lo0 = t * 16;
  const int NKT = I_DIM / 32;  // 44

  auto stA = [&](int z) {
    if (z < NKT) {
      char* d = smem + (z & 3) * 32768;
      int k = z * 32;
      gload16(asrc0 + k, d + lo0);
      gload16(asrc1 + k, d + 8192 + lo0);
    }
  };
  auto stB = [&](int z) {
    if (z < NKT) {
      char* d = smem + (z & 3) * 32768 + 16384;
      int k = z * 32;
      gload16(bsrc0 + k, d + lo0);
      gload16(bsrc1 + k, d + 8192 + lo0);
    }
  };

  int aoff[8], boff[4];
#pragma unroll
  for (int mf = 0; mf < 8; ++mf) aoff[mf] = swz_off(wr * 128 + mf * 16 + l15, l4);
#pragma unroll
  for (int nf = 0; nf < 4; ++nf) boff[nf] = swz_off(wc * 64 + nf * 16 + l15, l4);

  f32x4 acc[8][4];
  f32x4 zero = {0.f, 0.f, 0.f, 0.f};
#pragma unroll
  for (int mf = 0; mf < 8; ++mf)
#pragma unroll
    for (int nf = 0; nf < 4; ++nf) acc[mf][nf] = zero;

  bf16x8 av0[4], av1[4], bv0[4], bv1[4];
  auto rdA = [&](bf16x8* dst, int T, int h) {
    char* base = smem + (T & 3) * 32768;
#pragma unroll
    for (int q = 0; q < 4; ++q) dst[q] = *(const bf16x8*)(base + aoff[h * 4 + q]);
  };
  auto rdB = [&](bf16x8* dst, int T) {
    char* base = smem + (T & 3) * 32768 + 16384;
#pragma unroll
    for (int nf = 0; nf < 4; ++nf) dst[nf] = *(const bf16x8*)(base + boff[nf]);
  };

  stB(0); stA(0); stB(1); stA(1); stB(2); stA(2);
  VM0();
  BAR();
  SCHED();
  rdA(av0, 0, 0); rdB(bv0, 0);

  const int NIT = NKT / 2;  // 22
  for (int it = 0; it < NIT; ++it) {
    int T0 = 2 * it, T1 = 2 * it + 1, T2n = 2 * it + 2;
    int zB = 2 * it + 3, zC = 2 * it + 4;
    rdA(av1, T0, 1);
    MM(av0, bv0, 0);
    stB(zB);
    SCHED(); VM6(); BAR(); SCHED();
    rdA(av0, T1, 0); rdB(bv1, T1);
    MM(av1, bv0, 1);
    stA(zB);
    SCHED(); BAR(); SCHED();
    rdA(av1, T1, 1);
    MM(av0, bv1, 0);
    stB(zC);
    SCHED(); VM6(); BAR(); SCHED();
    if (it + 1 < NIT) { rdA(av0, T2n, 0); rdB(bv0, T2n); }
    MM(av1, bv1, 1);
    stA(zC);
    SCHED(); BAR(); SCHED();
  }
  VM0();

#pragma unroll
  for (int mf = 0; mf < 8; ++mf)
#pragma unroll
    for (int r = 0; r < 4; ++r) {
      int idx = row0 + wr * 128 + mf * 16 + l4 * 4 + r;
      if (idx < limit) {
        float p;
        int tok;
        if (e == NE) { p = 1.f; tok = idx; }
        else {
          p = bp[e * N_TOK + idx];
          tok = btok[e * N_TOK + idx] & (N_TOK - 1);
        }
#pragma unroll
        for (int nf = 0; nf < 4; ++nf) {
          int col = c0 + wc * 64 + nf * 16 + l15;
          atomicAdd(&y[(size_t)tok * C_DIM + col], p * acc[mf][nf][r]);
        }
      }
    }
}

extern "C" void kernel_launch(void* const* d_in, const int* in_sizes, int n_in,
                              void* d_out, int out_size, void* d_ws, size_t ws_size,
                              hipStream_t stream) {
  const float* x = (const float*)d_in[0];
  const float* Wg = (const float*)d_in[1];
  const float* W1 = (const float*)d_in[2];
  const float* W2 = (const float*)d_in[3];
  const float* W3 = (const float*)d_in[4];
  const float* Ws1 = (const float*)d_in[5];
  const float* Ws2 = (const float*)d_in[6];
  const float* Ws3 = (const float*)d_in[7];
  float* y = (float*)d_out;
  char* ws = (char*)d_ws;

  int* cnt = (int*)(ws + CNT_OFF);
  int* offs = (int*)(ws + OFFS_OFF);
  int* tt = (int*)(ws + TT_OFF);
  int* btok = (int*)(ws + BTOK_OFF);
  float* bp = (float*)(ws + BP_OFF);
  int* tsel = (int*)(ws + TSEL_OFF);
  float* tp0 = (float*)(ws + TP0_OFF);
  float* tp1 = (float*)(ws + TP1_OFF);
  bf16* xb = (bf16*)(ws + XB_OFF);
  bf16* wb1 = (bf16*)(ws + WB1_OFF);
  bf16* wb2 = (bf16*)(ws + WB2_OFF);
  bf16* wb3 = (bf16*)(ws + WB3_OFF);
  bf16* H = (bf16*)(ws + H_OFF);

  // y must start at zero every call (stage2 is all-atomic)
  hipMemsetAsync(y, 0, (size_t)N_TOK * C_DIM * 4, stream);

  logits_kernel<<<N_TOK / 4, 256, 0, stream>>>(x, Wg, tsel, tp0, tp1);
  bucketize_kernel<<<NE, 1024, 0, stream>>>(tsel, tp0, tp1, cnt, btok, bp);
  offsets_kernel<<<1, 64, 0, stream>>>(cnt, offs, tt);

  convert_all_kernel<<<2048, 256, 0, stream>>>(x, W1, Ws1, W2, Ws2, W3, Ws3, ws);

  stage1_kernel<<<1232, 512, 0, stream>>>(xb, wb1, wb2, cnt, offs, tt, btok, H);
  stage2_kernel<<<448, 512, 0, stream>>>(H, wb3, cnt, offs, tt, btok, bp, y);
}